// Round 9
// baseline (197.941 us; speedup 1.0000x reference)
//
#include <hip/hip_runtime.h>
#include <hip/hip_bf16.h>
#include <math.h>

#define BB 2
#define CC 1024
#define TT 2048
#define HH 16
#define DD 64

using short8   = __attribute__((ext_vector_type(8))) short;
using floatx4  = __attribute__((ext_vector_type(4))) float;
using floatx16 = __attribute__((ext_vector_type(16))) float;
using uint2v   = __attribute__((ext_vector_type(2))) unsigned int;
typedef unsigned short ushort_t;

#define MFMA(a, b, c) __builtin_amdgcn_mfma_f32_16x16x32_bf16((a), (b), (c), 0, 0, 0)
#define MFMA32(a, b, c) __builtin_amdgcn_mfma_f32_32x32x16_bf16((a), (b), (c), 0, 0, 0)

// Q pre-scale: SCALE * log2(e) so attn softmax runs in exp2 domain.
#define QSC 0.18033688011112042f

// bf16-domain Schraudolph: f = fma(s,128,PMAGIC) with f in [2^23,2^24) means
// low16(bits(f)) == round(s*128 + 16249) == bf16 encoding of ~2^s.
// At s==0 this yields bf16 0x3F79 = 0.97265625 exactly (PZERO_BF).
#define PMAGIC   8404857.0f   /* 2^23 + 16249 */
#define PZERO_BF 0.97265625f

__device__ __forceinline__ ushort_t f2bf(float f) {          // RNE (O-path)
    unsigned int u = __float_as_uint(f);
    u += 0x7FFFu + ((u >> 16) & 1u);
    return (ushort_t)(u >> 16);
}
__device__ __forceinline__ float bf2f(ushort_t h) {
    return __uint_as_float(((unsigned int)h) << 16);
}
__device__ __forceinline__ ushort_t f2bf_t(float f) {        // truncation
    return (ushort_t)(__float_as_uint(f) >> 16);
}
// single v_perm_b32: pack high halves of two floats (truncation to bf16)
__device__ __forceinline__ unsigned int packtrunc(float a, float b) {
    return __builtin_amdgcn_perm(__float_as_uint(b), __float_as_uint(a),
                                 0x07060302u);
}
// bf16-domain Schraudolph exp2 of two scores -> packed bf16x2.
__device__ __forceinline__ unsigned int pack2bf_exp(float s0, float s1) {
    float f0 = fmaf(s0, 128.0f, PMAGIC);
    float f1 = fmaf(s1, 128.0f, PMAGIC);
    return __builtin_amdgcn_perm(__float_as_uint(f1), __float_as_uint(f0),
                                 0x05040100u);
}
// async global->LDS, 16B per lane, dest = uniform base + lane*16
__device__ __forceinline__ void load_lds16(const void* g, void* s) {
    __builtin_amdgcn_global_load_lds(
        (const __attribute__((address_space(1))) void*)g,
        (__attribute__((address_space(3))) void*)s, 16, 0, 0);
}

// ---- workspace byte offsets (bf16 arena starts at 64KB) --------------------
static constexpr size_t B0       = 65536;
static constexpr size_t XT_OFF   = B0;                       // [B][T][C] bf16; later reused for OT
static constexpr size_t WQKV_OFF = XT_OFF   + 8388608;       // [3072][1024]
static constexpr size_t WP_OFF   = WQKV_OFF + 6291456;       // [1024][1024]
static constexpr size_t Q_OFF    = WP_OFF   + 2097152;       // [B][H][T][D]
static constexpr size_t K_OFF    = Q_OFF    + 8388608;
static constexpr size_t V_OFF    = K_OFF    + 8388608;       // [B][C][T]
static constexpr size_t OP_OFF   = V_OFF    + 8388608;       // Opart[2][B][T][C] bf16
static constexpr size_t ML_OFF   = OP_OFF   + 16777216;      // l[2][B][H][T] fp32

// ---------------------------------------------------------------------------
// Merged prep kernel (unchanged).
// ---------------------------------------------------------------------------
__global__ __launch_bounds__(256) void prep_kernel(
    const float* __restrict__ x, const float* __restrict__ Wq,
    const float* __restrict__ Wk, const float* __restrict__ Wv,
    const float* __restrict__ Wp, const unsigned int* __restrict__ mraw,
    ushort_t* __restrict__ XT, ushort_t* __restrict__ WQKV,
    ushort_t* __restrict__ WP, float* __restrict__ maskf,
    int* __restrict__ nmcnt, float* __restrict__ out_tail) {
    __shared__ float tile[64][65];
    const int bid = blockIdx.x;
    const int tid = threadIdx.x;
    if (bid < 4096) {
        const int idx = bid * 256 + tid;  // quad index
        if (idx < 786432) {
            int row = idx >> 8;
            int qc  = idx & 255;
            const float* src = row < 1024 ? Wq : (row < 2048 ? Wk : Wv);
            float4 v = *(const float4*)&src[(size_t)(row & 1023) * CC + qc * 4];
            ushort4 pk; pk.x = f2bf(v.x); pk.y = f2bf(v.y);
            pk.z = f2bf(v.z); pk.w = f2bf(v.w);
            *(ushort4*)&WQKV[(size_t)idx * 4] = pk;
        } else {
            int j = idx - 786432;
            float4 v = *(const float4*)&Wp[(size_t)j * 4];
            ushort4 pk; pk.x = f2bf(v.x); pk.y = f2bf(v.y);
            pk.z = f2bf(v.z); pk.w = f2bf(v.w);
            *(ushort4*)&WP[(size_t)j * 4] = pk;
        }
    } else if (bid < 5120) {
        const int xb = bid - 4096;
        const int t0 = (xb & 31) * 64, c0 = ((xb >> 5) & 15) * 64, b = xb >> 9;
        const int tc = tid & 15, tr = tid >> 4;
        #pragma unroll
        for (int p = 0; p < 4; p++) {
            int cl = tr + p * 16;
            float4 v = *(const float4*)&x[((size_t)b * CC + c0 + cl) * TT + t0 + tc * 4];
            tile[cl][tc * 4 + 0] = v.x; tile[cl][tc * 4 + 1] = v.y;
            tile[cl][tc * 4 + 2] = v.z; tile[cl][tc * 4 + 3] = v.w;
        }
        __syncthreads();
        #pragma unroll
        for (int p = 0; p < 4; p++) {
            int tl = tr + p * 16;
            ushort4 pk;
            pk.x = f2bf(tile[tc * 4 + 0][tl]);
            pk.y = f2bf(tile[tc * 4 + 1][tl]);
            pk.z = f2bf(tile[tc * 4 + 2][tl]);
            pk.w = f2bf(tile[tc * 4 + 3][tl]);
            *(ushort4*)&XT[((size_t)b * TT + t0 + tl) * CC + c0 + tc * 4] = pk;
        }
    } else {
        __shared__ int ev_bf16, ev_bool, cnt;
        const int mb = bid - 5120;      // 0..15
        if (tid == 0) { ev_bf16 = 0; ev_bool = 0; cnt = 0; }
        __syncthreads();
        for (int i = tid; i < 1024; i += 256) {
            unsigned int w = mraw[i];
            if ((w & 0xFFFFu) == 0x3F80u) atomicOr(&ev_bf16, 1);
            if ((w & 0xFFFFFF00u) != 0u && w != 0x3F800000u) atomicOr(&ev_bool, 1);
        }
        __syncthreads();
        const int mode = ev_bf16 ? 2 : (ev_bool ? 1 : 0);
        const int e = mb * 256 + tid;
        bool on;
        if (mode == 2)      on = ((const ushort_t*)mraw)[e] != 0;
        else if (mode == 1) on = ((const unsigned char*)mraw)[e] != 0;
        else                on = mraw[e] != 0;
        maskf[e]    = on ? 1.0f : 0.0f;
        out_tail[e] = on ? 1.0f : 0.0f;
        if (!on) atomicAdd(&cnt, 1);
        __syncthreads();
        if (tid == 0) nmcnt[mb] = cnt;
    }
}

// ---------------------------------------------------------------------------
// Fused QKV GEMM v3: + XCD-aware block clustering. All 24 m-blocks sharing
// one 256KB B-tile (n0,b) land on ONE XCD consecutively (m fastest) -> B-tile
// L2-resident instead of re-fetched per XCD. Pipelined staging kept (neutral
// but harmless at 3 blocks/CU).
// ---------------------------------------------------------------------------
__global__ __launch_bounds__(256) void gemm_qkv_kernel(
    const ushort_t* __restrict__ Wqkv, const float* __restrict__ bq,
    const float* __restrict__ bk, const float* __restrict__ bv,
    const ushort_t* __restrict__ XT, const float* __restrict__ maskf,
    ushort_t* __restrict__ Qo, ushort_t* __restrict__ Ko,
    ushort_t* __restrict__ Vo) {
    __shared__ ushort_t As[2][128][32];
    __shared__ ushort_t Bs[2][128][32];
    __shared__ float biasS[128];

    // ---- XCD decode: bid = xcd + 8*(mi + 24*gi); g=(gi<<3)|xcd = n + 16*b
    const unsigned int bid = blockIdx.x;      // 0..767
    const unsigned int xcd = bid & 7u;
    const unsigned int r   = bid >> 3;        // 0..95
    const unsigned int mi  = r % 24u;         // m-block (fastest within XCD)
    const unsigned int gi  = r / 24u;         // 0..3
    const unsigned int g   = (gi << 3) | xcd; // 0..31
    const int n0 = (int)(g & 15u) * 128;
    const int b  = (int)(g >> 4);
    const int m0 = (int)mi * 128;

    const int tid = threadIdx.x;
    const int lane = tid & 63;
    const int w = tid >> 6;
    const int wm = (w & 1) * 64, wn = (w >> 1) * 64;
    const int la = lane & 15, lg = lane >> 4;
    const int region = m0 >> 10;  // 0=q 1=k 2=v

    const float* bsrc = region == 0 ? (bq + m0)
                      : (region == 1 ? (bk + m0 - 1024) : (bv + m0 - 2048));
    if (tid < 128) biasS[tid] = bsrc[tid];

    float csc[4];
    #pragma unroll
    for (int nt = 0; nt < 4; nt++) {
        const int t = n0 + wn + nt * 16 + la;
        csc[nt] = (region == 0) ? QSC : maskf[b * TT + t];
    }

    floatx4 zero4 = {0.f, 0.f, 0.f, 0.f};
    floatx4 acc[4][4];
    #pragma unroll
    for (int mt = 0; mt < 4; mt++)
        #pragma unroll
        for (int nt = 0; nt < 4; nt++) acc[mt][nt] = zero4;

    const ushort_t* Abase = Wqkv + (size_t)m0 * CC;
    const ushort_t* Bbase = XT + ((size_t)b * TT + n0) * CC;
    const int rl = lane >> 2;
    const int cl = (lane & 3) * 8;

    // prologue: stage K-step 0 into buf 0
    #pragma unroll
    for (int c = 0; c < 2; c++) {
        int row = w * 32 + c * 16;
        load_lds16(Abase + (size_t)(row + rl) * CC + cl, &As[0][row][0]);
        load_lds16(Bbase + (size_t)(row + rl) * CC + cl, &Bs[0][row][0]);
    }
    __syncthreads();   // drains vmcnt(0): step 0 staged (also covers biasS)

    for (int kt = 0; kt < 32; kt++) {
        const int cur = kt & 1;
        // issue loads for step kt+1 AFTER the barrier: in flight during MFMAs
        if (kt < 31) {
            const int k0n = (kt + 1) * 32;
            #pragma unroll
            for (int c = 0; c < 2; c++) {
                int row = w * 32 + c * 16;
                load_lds16(Abase + (size_t)(row + rl) * CC + k0n + cl,
                           &As[cur ^ 1][row][0]);
                load_lds16(Bbase + (size_t)(row + rl) * CC + k0n + cl,
                           &Bs[cur ^ 1][row][0]);
            }
        }
        short8 af[4], bf[4];
        #pragma unroll
        for (int mt = 0; mt < 4; mt++)
            af[mt] = *(const short8*)&As[cur][wm + mt * 16 + la][lg * 8];
        #pragma unroll
        for (int nt = 0; nt < 4; nt++)
            bf[nt] = *(const short8*)&Bs[cur][wn + nt * 16 + la][lg * 8];
        __builtin_amdgcn_s_setprio(1);
        #pragma unroll
        for (int mt = 0; mt < 4; mt++)
            #pragma unroll
            for (int nt = 0; nt < 4; nt++)
                acc[mt][nt] = MFMA(af[mt], bf[nt], acc[mt][nt]);
        __builtin_amdgcn_s_setprio(0);
        // end barrier: drains own glds (next buf ready) AND ensures all waves
        // finished reading buf[cur] before step kt+1 overwrites it.
        if (kt < 31) __syncthreads();
    }

    #pragma unroll
    for (int mt = 0; mt < 4; mt++) {
        const int lm = wm + mt * 16 + lg * 4;
        const int gm = m0 + lm;
        #pragma unroll
        for (int nt = 0; nt < 4; nt++) {
            const int t = n0 + wn + nt * 16 + la;
            const float sc = csc[nt];
            float v0 = (acc[mt][nt][0] + biasS[lm + 0]) * sc;
            float v1 = (acc[mt][nt][1] + biasS[lm + 1]) * sc;
            float v2 = (acc[mt][nt][2] + biasS[lm + 2]) * sc;
            float v3 = (acc[mt][nt][3] + biasS[lm + 3]) * sc;
            if (region < 2) {
                int mq = gm & 1023;
                int hh = mq >> 6, db = mq & 63;
                ushort_t* dst = (region == 0 ? Qo : Ko)
                              + (((size_t)b * HH + hh) * TT + t) * DD + db;
                uint2 pk;
                pk.x = packtrunc(v0, v1);
                pk.y = packtrunc(v2, v3);
                *(uint2*)dst = pk;
            } else {
                int c = gm & 1023;
                Vo[((size_t)b * CC + c + 0) * TT + t] = f2bf_t(v0);
                Vo[((size_t)b * CC + c + 1) * TT + t] = f2bf_t(v1);
                Vo[((size_t)b * CC + c + 2) * TT + t] = f2bf_t(v2);
                Vo[((size_t)b * CC + c + 3) * TT + t] = f2bf_t(v3);
            }
        }
    }
}

// ---------------------------------------------------------------------------
// Flash attention v11b (R5 exact — best measured: 42.2-42.8us). UNCHANGED.
// ---------------------------------------------------------------------------
__global__ __launch_bounds__(256, 4) void attn_kernel(
    const ushort_t* __restrict__ Qg, const ushort_t* __restrict__ Kg,
    const ushort_t* __restrict__ Vg, const int* __restrict__ nmcnt,
    ushort_t* __restrict__ Opart, float* __restrict__ lbuf) {
    // bytes [0,16384): K bufs (p*8192); [16384,32768): V bufs (16384+p*8192)
    __shared__ __align__(16) char ldsbuf[32768];

    // ---- XCD-aware decode: bid = xcd + 8*(x + 16*j), g = (j<<3)|xcd ----
    const unsigned int bid = blockIdx.x;          // 0..1023
    const unsigned int xcd = bid & 7u;
    const unsigned int rr  = bid >> 3;            // 0..127
    const unsigned int x   = rr & 15u;            // q-tile index
    const unsigned int j   = rr >> 4;             // 0..7
    const unsigned int g   = (j << 3) | xcd;      // 0..63 == hh + 16*z
    const int hh  = (int)(g & 15u);
    const int z   = (int)(g >> 4);                // 0..3 == sp + 2*b
    const int sp  = z & 1, b = z >> 1;
    const int t0  = (int)x * 128;

    const int j0base = sp * (TT / 2);
    const int tid  = threadIdx.x;
    const int lane = tid & 63;
    const int w    = tid >> 6;
    const int ln31 = lane & 31;
    const int h    = lane >> 5;
    const size_t qkbase = ((size_t)b * HH + hh) * TT * DD;
    const size_t vbase  = ((size_t)b * CC + hh * DD) * TT;

    const int tq = t0 + w * 32 + ln31;
    short8 qreg[4];
    {
        const ushort_t* qp = Qg + qkbase + (size_t)tq * DD + h * 8;
        #pragma unroll
        for (int kc = 0; kc < 4; kc++)
            qreg[kc] = *(const short8*)(qp + kc * 16);
    }

    // ---- staging geometry (rotation swizzle) ----
    const int i3   = lane >> 3;                          // 0..7 (row within 8)
    const int swzb = (((lane & 7) + 8 - i3) & 7) << 4;   // rotated byte-in-row
    const char* ks0 = (const char*)(Kg + qkbase + (size_t)(j0base + 16 * w + i3) * DD) + swzb;
    const char* vs0 = (const char*)(Vg + vbase + (size_t)(16 * w + i3) * TT + j0base) + swzb;
    char* kd = ldsbuf + 2 * w * 1024;                    // wave-uniform dests
    char* vd = ldsbuf + 16384 + 2 * w * 1024;

    // ---- rotated read addresses: G[row][chunk cc] lives at chunk (cc+row)&7
    int ka[4];
    #pragma unroll
    for (int kc = 0; kc < 4; kc++)
        ka[kc] = ln31 * 128 + (((kc * 2 + h + ln31) & 7) << 4);

    floatx16 zero16 = {0.f,0.f,0.f,0.f,0.f,0.f,0.f,0.f,
                       0.f,0.f,0.f,0.f,0.f,0.f,0.f,0.f};
    floatx16 oacc[2];
    oacc[0] = zero16; oacc[1] = zero16;
    floatx16 lacc = zero16;              // every reg = sum_k p[k][q]
    short8 ones8;
    #pragma unroll
    for (int i = 0; i < 8; i++) ones8[i] = (short)0x3F80;   // bf16 1.0

    // prologue: stage tile 0 into buf 0
    load_lds16(ks0,          kd);
    load_lds16(ks0 + 1024,   kd + 1024);     // q=1: +8 K rows = +1KB contiguous
    load_lds16(vs0,          vd);
    load_lds16(vs0 + 32768,  vd + 1024);     // q=1: +8 V rows = +8*TT*2 bytes
    ks0 += 8192; vs0 += 128;
    __syncthreads();   // drains vmcnt(0): tile 0 staged

    #pragma unroll 2
    for (int kt = 0; kt < 16; kt++) {
        const int pp = (kt & 1) * 8192;          // current buffer byte offset
        const int pn = 8192 - pp;                // next buffer byte offset
        // issue stage of tile kt+1 first: in flight during compute
        if (kt < 15) {
            load_lds16(ks0,         kd + pn);
            load_lds16(ks0 + 1024,  kd + pn + 1024);
            load_lds16(vs0,         vd + pn);
            load_lds16(vs0 + 32768, vd + pn + 1024);
            ks0 += 8192; vs0 += 128;
        }

        // ---- S^T = K · Q^T ----
        floatx16 sacc[2];
        sacc[0] = zero16; sacc[1] = zero16;
        __builtin_amdgcn_s_setprio(1);
        #pragma unroll
        for (int kc = 0; kc < 4; kc++) {
            short8 kf0 = *(const short8*)(ldsbuf + ka[kc] + pp);
            short8 kf1 = *(const short8*)(ldsbuf + ka[kc] + pp + 4096);
            sacc[0] = MFMA32(kf0, qreg[kc], sacc[0]);
            sacc[1] = MFMA32(kf1, qreg[kc], sacc[1]);
        }
        __builtin_amdgcn_s_setprio(0);

        // ---- bf16-domain Schraudolph: p_bf16 = low16(fma(s,128,PMAGIC)) ----
        unsigned int pd[16];
        #pragma unroll
        for (int mt = 0; mt < 2; mt++)
            #pragma unroll
            for (int g2 = 0; g2 < 4; g2++) {
                pd[mt * 8 + g2 * 2 + 0] =
                    pack2bf_exp(sacc[mt][g2 * 4 + 0], sacc[mt][g2 * 4 + 1]);
                pd[mt * 8 + g2 * 2 + 1] =
                    pack2bf_exp(sacc[mt][g2 * 4 + 2], sacc[mt][g2 * 4 + 3]);
            }

        // ---- PV: B-frag via permlane32_swap; l-sum via ones-MFMA ----
        __builtin_amdgcn_s_setprio(1);
        #pragma unroll
        for (int kc = 0; kc < 4; kc++) {
            const int base = (kc >> 1) * 8 + (kc & 1) * 4;
            uint2v r02 = __builtin_amdgcn_permlane32_swap(
                pd[base + 0], pd[base + 2], false, false);
            uint2v r13 = __builtin_amdgcn_permlane32_swap(
                pd[base + 1], pd[base + 3], false, false);
            int4 fi;
            fi.x = (int)r02[0];
            fi.y = (int)r13[0];
            fi.z = (int)r02[1];
            fi.w = (int)r13[1];
            short8 pf = *(short8*)&fi;
            lacc = MFMA32(ones8, pf, lacc);   // all rows = sum over k (both halves)
            short8 vf0 = *(const short8*)(ldsbuf + ka[kc] + pp + 16384);
            short8 vf1 = *(const short8*)(ldsbuf + ka[kc] + pp + 16384 + 4096);
            oacc[0] = MFMA32(vf0, pf, oacc[0]);
            oacc[1] = MFMA32(vf1, pf, oacc[1]);
        }
        __builtin_amdgcn_s_setprio(0);

        // barrier drains this wave's glds (vmcnt(0)) -> next buffer ready,
        // and guarantees all waves done reading buf pp before it's restaged.
        if (kt < 15) __syncthreads();
    }

    // lacc[0] holds the full split-sum over all 1024 keys. Remove masked
    // keys' exact bf16(approx 2^0) = 0.97265625 contributions.
    float lsum = lacc[0];
    {
        const int r4 = (b * 2 + sp) * 4;
        int nm = nmcnt[r4] + nmcnt[r4 + 1] + nmcnt[r4 + 2] + nmcnt[r4 + 3];
        lsum -= (float)nm * PZERO_BF;
    }

    // ---- epilogue: Opart = O_s/l_s (bf16 RNE — O-path stays unbiased) ----
    const float inv = lsum > 0.0f ? 1.0f / lsum : 0.0f;
    ushort_t* OP = Opart + (size_t)sp * ((size_t)BB * TT * CC)
                 + ((size_t)b * TT + tq) * CC + hh * 64;
    #pragma unroll
    for (int mt = 0; mt < 2; mt++)
        #pragma unroll
        for (int g2 = 0; g2 < 4; g2++) {
            int db = mt * 32 + g2 * 8 + h * 4;
            ushort4 pk;
            pk.x = f2bf(oacc[mt][g2 * 4 + 0] * inv);
            pk.y = f2bf(oacc[mt][g2 * 4 + 1] * inv);
            pk.z = f2bf(oacc[mt][g2 * 4 + 2] * inv);
            pk.w = f2bf(oacc[mt][g2 * 4 + 3] * inv);
            *(ushort4*)&OP[db] = pk;
        }
    if (h == 0)
        lbuf[(((size_t)sp * BB + b) * HH + hh) * TT + tq] = lsum;
}

// ---------------------------------------------------------------------------
// Combine splits: OT = w0*P0 + w1*P1, w_s = l_s/(l0+l1).
// ---------------------------------------------------------------------------
__global__ __launch_bounds__(256) void combine_kernel(
    const ushort_t* __restrict__ Opart, const float* __restrict__ lbuf,
    ushort_t* __restrict__ OT) {
    const size_t idx = ((size_t)blockIdx.x * 256 + threadIdx.x) * 8;
    const int c0 = (int)(idx & (CC - 1));
    const int t  = (int)((idx >> 10) & (TT - 1));
    const int b  = (int)(idx >> 21);
    const int hh = c0 >> 6;
    const float l0 = lbuf[(((size_t)0 * BB + b) * HH + hh) * TT + t];
    const float l1 = lbuf[(((size_t)1 * BB + b) * HH + hh) * TT + t];
    const float sum = l0 + l1;
    const float ws = sum > 0.0f ? 1.0f / sum : 0.0f;
    const float w0 = l0 * ws, w1 = l1 * ws;
    const ushort_t* P0 = Opart + idx;
    const ushort_t* P1 = Opart + (size_t)BB * TT * CC + idx;
    ushort4 a0 = *(const ushort4*)(P0);
    ushort4 a1 = *(const ushort4*)(P0 + 4);
    ushort4 b0 = *(const ushort4*)(P1);
    ushort4 b1 = *(const ushort4*)(P1 + 4);
    ushort4 o0, o1;
    o0.x = f2bf(w0 * bf2f(a0.x) + w1 * bf2f(b0.x));
    o0.y = f2bf(w0 * bf2f(a0.y) + w1 * bf2f(b0.y));
    o0.z = f2bf(w0 * bf2f(a0.z) + w1 * bf2f(b0.z));
    o0.w = f2bf(w0 * bf2f(a0.w) + w1 * bf2f(b0.w));
    o1.x = f2bf(w0 * bf2f(a1.x) + w1 * bf2f(b1.x));
    o1.y = f2bf(w0 * bf2f(a1.y) + w1 * bf2f(b1.y));
    o1.z = f2bf(w0 * bf2f(a1.z) + w1 * bf2f(b1.z));
    o1.w = f2bf(w0 * bf2f(a1.w) + w1 * bf2f(b1.w));
    *(ushort4*)&OT[idx]     = o0;
    *(ushort4*)&OT[idx + 4] = o1;
}

// ---------------------------------------------------------------------------
// Output GEMM v3: + XCD-aware block clustering. All 16 m-blocks sharing one
// 256KB OT B-tile (n0,b) land on ONE XCD consecutively -> B-tile L2-resident.
// ---------------------------------------------------------------------------
__global__ __launch_bounds__(256) void gemm_out_kernel(
    const ushort_t* __restrict__ WP, const ushort_t* __restrict__ OT,
    const float* __restrict__ bp, const float* __restrict__ maskf,
    float* __restrict__ out) {
    __shared__ ushort_t As[2][64][32];
    __shared__ ushort_t Bs[2][128][32];
    __shared__ float biasS[64];

    // ---- XCD decode: bid = xcd + 8*(mi + 16*gi); g=(gi<<3)|xcd = n + 16*b
    const unsigned int bid = blockIdx.x;      // 0..511
    const unsigned int xcd = bid & 7u;
    const unsigned int r   = bid >> 3;        // 0..63
    const unsigned int mi  = r & 15u;         // m-block (fastest within XCD)
    const unsigned int gi  = r >> 4;          // 0..3
    const unsigned int g   = (gi << 3) | xcd; // 0..31
    const int n0 = (int)(g & 15u) * 128;
    const int b  = (int)(g >> 4);
    const int m0 = (int)mi * 64;

    const int tid = threadIdx.x;
    const int lane = tid & 63;
    const int w = tid >> 6;
    const int wm = (w & 1) * 32, wn = (w >> 1) * 64;
    const int la = lane & 15, lg = lane >> 4;

    if (tid < 64) biasS[tid] = bp[m0 + tid];

    floatx4 zero4 = {0.f, 0.f, 0.f, 0.f};
    floatx4 acc[2][4];
    #pragma unroll
    for (int mt = 0; mt < 2; mt++)
        #pragma unroll
        for (int nt = 0; nt < 4; nt++) acc[mt][nt] = zero4;

    const int rl = lane >> 2;
    const int cl = (lane & 3) * 8;
    const ushort_t* Bbase = OT + ((size_t)b * TT + n0) * CC;

    // prologue: stage K-step 0 into buf 0
    {
        int row = w * 16;
        load_lds16(WP + (size_t)(m0 + row + rl) * CC + cl, &As[0][row][0]);
    }
    #pragma unroll
    for (int c = 0; c < 2; c++) {
        int row = w * 32 + c * 16;
        load_lds16(Bbase + (size_t)(row + rl) * CC + cl, &Bs[0][row][0]);
    }
    __syncthreads();

    for (int kt = 0; kt < 32; kt++) {
        const int cur = kt & 1;
        if (kt < 31) {
            const int k0n = (kt + 1) * 32;
            {
                int row = w * 16;
                load_lds16(WP + (size_t)(m0 + row + rl) * CC + k0n + cl,
                           &As[cur ^ 1][row][0]);
            }
            #pragma unroll
            for (int c = 0; c < 2; c++) {
                int row = w * 32 + c * 16;
                load_lds16(Bbase + (size_t)(row + rl) * CC + k0n + cl,
                           &Bs[cur ^ 1][row][0]);
            }
        }
        short8 af[2], bf[4];
        #pragma unroll
        for (int mt = 0; mt < 2; mt++)
            af[mt] = *(const short8*)&As[cur][wm + mt * 16 + la][lg * 8];
        #pragma unroll
        for (int nt = 0; nt < 4; nt++)
            bf[nt] = *(const short8*)&Bs[cur][wn + nt * 16 + la][lg * 8];
        __builtin_amdgcn_s_setprio(1);
        #pragma unroll
        for (int mt = 0; mt < 2; mt++)
            #pragma unroll
            for (int nt = 0; nt < 4; nt++)
                acc[mt][nt] = MFMA(af[mt], bf[nt], acc[mt][nt]);
        __builtin_amdgcn_s_setprio(0);
        if (kt < 31) __syncthreads();
    }

    #pragma unroll
    for (int mt = 0; mt < 2; mt++) {
        const int lm = wm + mt * 16 + lg * 4;
        #pragma unroll
        for (int nt = 0; nt < 4; nt++) {
            const int t = n0 + wn + nt * 16 + la;
            const float mk = maskf[b * TT + t];
            #pragma unroll
            for (int r2 = 0; r2 < 4; r2++)
                out[((size_t)b * CC + m0 + lm + r2) * TT + t] =
                    (acc[mt][nt][r2] + biasS[lm + r2]) * mk;
        }
    }
}

// ---------------------------------------------------------------------------
extern "C" void kernel_launch(void* const* d_in, const int* in_sizes, int n_in,
                              void* d_out, int out_size, void* d_ws,
                              size_t ws_size, hipStream_t stream) {
    const float* x    = (const float*)d_in[0];
    const void*  mask = d_in[1];
    const float* Wq   = (const float*)d_in[2];
    const float* bq   = (const float*)d_in[3];
    const float* Wk   = (const float*)d_in[4];
    const float* bk   = (const float*)d_in[5];
    const float* Wv   = (const float*)d_in[6];
    const float* bv   = (const float*)d_in[7];
    const float* Wp   = (const float*)d_in[8];
    const float* bp   = (const float*)d_in[9];

    float* out  = (float*)d_out;
    float* wsf  = (float*)d_ws;
    int* nmcnt  = (int*)d_ws + 16;     // 16 per-block masked counts
    float* maskf = wsf + 1024;
    char* wsb = (char*)d_ws;
    ushort_t* XT    = (ushort_t*)(wsb + XT_OFF);   // also final OT
    ushort_t* WQKV  = (ushort_t*)(wsb + WQKV_OFF);
    ushort_t* WPb   = (ushort_t*)(wsb + WP_OFF);
    ushort_t* Qb    = (ushort_t*)(wsb + Q_OFF);
    ushort_t* Kb    = (ushort_t*)(wsb + K_OFF);
    ushort_t* Vb    = (ushort_t*)(wsb + V_OFF);
    ushort_t* Opart = (ushort_t*)(wsb + OP_OFF);
    float*    lbuf  = (float*)(wsb + ML_OFF);

    prep_kernel<<<5136, 256, 0, stream>>>(x, Wq, Wk, Wv, Wp,
                                          (const unsigned int*)mask, XT, WQKV,
                                          WPb, maskf, nmcnt,
                                          out + (size_t)BB * CC * TT);

    gemm_qkv_kernel<<<dim3(768), 256, 0, stream>>>(
        WQKV, bq, bk, bv, XT, maskf, Qb, Kb, Vb);

    attn_kernel<<<dim3(1024), 256, 0, stream>>>(
        Qb, Kb, Vb, nmcnt, Opart, lbuf);

    combine_kernel<<<2048, 256, 0, stream>>>(Opart, lbuf, XT);

    gemm_out_kernel<<<dim3(512), 256, 0, stream>>>(
        WPb, XT, bp, maskf, out);
}

// Round 10
// 190.251 us; speedup vs baseline: 1.0404x; 1.0404x over previous
//
#include <hip/hip_runtime.h>
#include <hip/hip_bf16.h>
#include <math.h>

#define BB 2
#define CC 1024
#define TT 2048
#define HH 16
#define DD 64

using short8   = __attribute__((ext_vector_type(8))) short;
using floatx4  = __attribute__((ext_vector_type(4))) float;
using floatx16 = __attribute__((ext_vector_type(16))) float;
using uint2v   = __attribute__((ext_vector_type(2))) unsigned int;
typedef unsigned short ushort_t;

#define MFMA(a, b, c) __builtin_amdgcn_mfma_f32_16x16x32_bf16((a), (b), (c), 0, 0, 0)
#define MFMA32(a, b, c) __builtin_amdgcn_mfma_f32_32x32x16_bf16((a), (b), (c), 0, 0, 0)

// Q pre-scale: SCALE * log2(e) so attn softmax runs in exp2 domain.
#define QSC 0.18033688011112042f

// bf16-domain Schraudolph: f = fma(s,128,PMAGIC) with f in [2^23,2^24) means
// low16(bits(f)) == round(s*128 + 16249) == bf16 encoding of ~2^s.
// At s==0 this yields bf16 0x3F79 = 0.97265625 exactly (PZERO_BF).
#define PMAGIC   8404857.0f   /* 2^23 + 16249 */
#define PZERO_BF 0.97265625f

__device__ __forceinline__ ushort_t f2bf(float f) {          // RNE (O-path)
    unsigned int u = __float_as_uint(f);
    u += 0x7FFFu + ((u >> 16) & 1u);
    return (ushort_t)(u >> 16);
}
__device__ __forceinline__ float bf2f(ushort_t h) {
    return __uint_as_float(((unsigned int)h) << 16);
}
__device__ __forceinline__ ushort_t f2bf_t(float f) {        // truncation
    return (ushort_t)(__float_as_uint(f) >> 16);
}
// single v_perm_b32: pack high halves of two floats (truncation to bf16)
__device__ __forceinline__ unsigned int packtrunc(float a, float b) {
    return __builtin_amdgcn_perm(__float_as_uint(b), __float_as_uint(a),
                                 0x07060302u);
}
// bf16-domain Schraudolph exp2 of two scores -> packed bf16x2.
__device__ __forceinline__ unsigned int pack2bf_exp(float s0, float s1) {
    float f0 = fmaf(s0, 128.0f, PMAGIC);
    float f1 = fmaf(s1, 128.0f, PMAGIC);
    return __builtin_amdgcn_perm(__float_as_uint(f1), __float_as_uint(f0),
                                 0x05040100u);
}
// async global->LDS, 16B per lane, dest = uniform base + lane*16
__device__ __forceinline__ void load_lds16(const void* g, void* s) {
    __builtin_amdgcn_global_load_lds(
        (const __attribute__((address_space(1))) void*)g,
        (__attribute__((address_space(3))) void*)s, 16, 0, 0);
}

// ---- workspace byte offsets (bf16 arena starts at 64KB) --------------------
static constexpr size_t B0       = 65536;
static constexpr size_t XT_OFF   = B0;                       // [B][T][C] bf16; later reused for OT
static constexpr size_t WQKV_OFF = XT_OFF   + 8388608;       // [3072][1024]
static constexpr size_t WP_OFF   = WQKV_OFF + 6291456;       // [1024][1024]
static constexpr size_t Q_OFF    = WP_OFF   + 2097152;       // [B][H][T][D]
static constexpr size_t K_OFF    = Q_OFF    + 8388608;
static constexpr size_t V_OFF    = K_OFF    + 8388608;       // [B][C][T]
static constexpr size_t OP_OFF   = V_OFF    + 8388608;       // Opart[2][B][T][C] bf16
static constexpr size_t ML_OFF   = OP_OFF   + 16777216;      // l[2][B][H][T] fp32

// ---------------------------------------------------------------------------
// Merged prep kernel (unchanged).
// ---------------------------------------------------------------------------
__global__ __launch_bounds__(256) void prep_kernel(
    const float* __restrict__ x, const float* __restrict__ Wq,
    const float* __restrict__ Wk, const float* __restrict__ Wv,
    const float* __restrict__ Wp, const unsigned int* __restrict__ mraw,
    ushort_t* __restrict__ XT, ushort_t* __restrict__ WQKV,
    ushort_t* __restrict__ WP, float* __restrict__ maskf,
    int* __restrict__ nmcnt, float* __restrict__ out_tail) {
    __shared__ float tile[64][65];
    const int bid = blockIdx.x;
    const int tid = threadIdx.x;
    if (bid < 4096) {
        const int idx = bid * 256 + tid;  // quad index
        if (idx < 786432) {
            int row = idx >> 8;
            int qc  = idx & 255;
            const float* src = row < 1024 ? Wq : (row < 2048 ? Wk : Wv);
            float4 v = *(const float4*)&src[(size_t)(row & 1023) * CC + qc * 4];
            ushort4 pk; pk.x = f2bf(v.x); pk.y = f2bf(v.y);
            pk.z = f2bf(v.z); pk.w = f2bf(v.w);
            *(ushort4*)&WQKV[(size_t)idx * 4] = pk;
        } else {
            int j = idx - 786432;
            float4 v = *(const float4*)&Wp[(size_t)j * 4];
            ushort4 pk; pk.x = f2bf(v.x); pk.y = f2bf(v.y);
            pk.z = f2bf(v.z); pk.w = f2bf(v.w);
            *(ushort4*)&WP[(size_t)j * 4] = pk;
        }
    } else if (bid < 5120) {
        const int xb = bid - 4096;
        const int t0 = (xb & 31) * 64, c0 = ((xb >> 5) & 15) * 64, b = xb >> 9;
        const int tc = tid & 15, tr = tid >> 4;
        #pragma unroll
        for (int p = 0; p < 4; p++) {
            int cl = tr + p * 16;
            float4 v = *(const float4*)&x[((size_t)b * CC + c0 + cl) * TT + t0 + tc * 4];
            tile[cl][tc * 4 + 0] = v.x; tile[cl][tc * 4 + 1] = v.y;
            tile[cl][tc * 4 + 2] = v.z; tile[cl][tc * 4 + 3] = v.w;
        }
        __syncthreads();
        #pragma unroll
        for (int p = 0; p < 4; p++) {
            int tl = tr + p * 16;
            ushort4 pk;
            pk.x = f2bf(tile[tc * 4 + 0][tl]);
            pk.y = f2bf(tile[tc * 4 + 1][tl]);
            pk.z = f2bf(tile[tc * 4 + 2][tl]);
            pk.w = f2bf(tile[tc * 4 + 3][tl]);
            *(ushort4*)&XT[((size_t)b * TT + t0 + tl) * CC + c0 + tc * 4] = pk;
        }
    } else {
        __shared__ int ev_bf16, ev_bool, cnt;
        const int mb = bid - 5120;      // 0..15
        if (tid == 0) { ev_bf16 = 0; ev_bool = 0; cnt = 0; }
        __syncthreads();
        for (int i = tid; i < 1024; i += 256) {
            unsigned int w = mraw[i];
            if ((w & 0xFFFFu) == 0x3F80u) atomicOr(&ev_bf16, 1);
            if ((w & 0xFFFFFF00u) != 0u && w != 0x3F800000u) atomicOr(&ev_bool, 1);
        }
        __syncthreads();
        const int mode = ev_bf16 ? 2 : (ev_bool ? 1 : 0);
        const int e = mb * 256 + tid;
        bool on;
        if (mode == 2)      on = ((const ushort_t*)mraw)[e] != 0;
        else if (mode == 1) on = ((const unsigned char*)mraw)[e] != 0;
        else                on = mraw[e] != 0;
        maskf[e]    = on ? 1.0f : 0.0f;
        out_tail[e] = on ? 1.0f : 0.0f;
        if (!on) atomicAdd(&cnt, 1);
        __syncthreads();
        if (tid == 0) nmcnt[mb] = cnt;
    }
}

// ---------------------------------------------------------------------------
// Fused QKV GEMM (proven R11). q pre-scaled by QSC; K,V masked columns zeroed.
// ---------------------------------------------------------------------------
__global__ __launch_bounds__(256) void gemm_qkv_kernel(
    const ushort_t* __restrict__ Wqkv, const float* __restrict__ bq,
    const float* __restrict__ bk, const float* __restrict__ bv,
    const ushort_t* __restrict__ XT, const float* __restrict__ maskf,
    ushort_t* __restrict__ Qo, ushort_t* __restrict__ Ko,
    ushort_t* __restrict__ Vo) {
    __shared__ ushort_t As[128][32];
    __shared__ ushort_t Bs[128][32];
    __shared__ float biasS[128];

    const int b = blockIdx.z;
    const int m0 = blockIdx.y * 128;
    const int n0 = blockIdx.x * 128;
    const int tid = threadIdx.x;
    const int lane = tid & 63;
    const int w = tid >> 6;
    const int wm = (w & 1) * 64, wn = (w >> 1) * 64;
    const int la = lane & 15, lg = lane >> 4;
    const int region = m0 >> 10;  // 0=q 1=k 2=v

    const float* bsrc = region == 0 ? (bq + m0)
                      : (region == 1 ? (bk + m0 - 1024) : (bv + m0 - 2048));
    if (tid < 128) biasS[tid] = bsrc[tid];

    float csc[4];
    #pragma unroll
    for (int nt = 0; nt < 4; nt++) {
        const int t = n0 + wn + nt * 16 + la;
        csc[nt] = (region == 0) ? QSC : maskf[b * TT + t];
    }

    floatx4 zero4 = {0.f, 0.f, 0.f, 0.f};
    floatx4 acc[4][4];
    #pragma unroll
    for (int mt = 0; mt < 4; mt++)
        #pragma unroll
        for (int nt = 0; nt < 4; nt++) acc[mt][nt] = zero4;

    const ushort_t* Abase = Wqkv + (size_t)m0 * CC;
    const ushort_t* Bbase = XT + ((size_t)b * TT + n0) * CC;
    const int rl = lane >> 2;
    const int cl = (lane & 3) * 8;

    for (int k0 = 0; k0 < CC; k0 += 32) {
        #pragma unroll
        for (int c = 0; c < 2; c++) {
            int row = w * 32 + c * 16;
            load_lds16(Abase + (size_t)(row + rl) * CC + k0 + cl, &As[row][0]);
            load_lds16(Bbase + (size_t)(row + rl) * CC + k0 + cl, &Bs[row][0]);
        }
        __syncthreads();
        short8 af[4], bf[4];
        #pragma unroll
        for (int mt = 0; mt < 4; mt++)
            af[mt] = *(const short8*)&As[wm + mt * 16 + la][lg * 8];
        #pragma unroll
        for (int nt = 0; nt < 4; nt++)
            bf[nt] = *(const short8*)&Bs[wn + nt * 16 + la][lg * 8];
        #pragma unroll
        for (int mt = 0; mt < 4; mt++)
            #pragma unroll
            for (int nt = 0; nt < 4; nt++)
                acc[mt][nt] = MFMA(af[mt], bf[nt], acc[mt][nt]);
        __syncthreads();
    }

    #pragma unroll
    for (int mt = 0; mt < 4; mt++) {
        const int lm = wm + mt * 16 + lg * 4;
        const int gm = m0 + lm;
        #pragma unroll
        for (int nt = 0; nt < 4; nt++) {
            const int t = n0 + wn + nt * 16 + la;
            const float sc = csc[nt];
            float v0 = (acc[mt][nt][0] + biasS[lm + 0]) * sc;
            float v1 = (acc[mt][nt][1] + biasS[lm + 1]) * sc;
            float v2 = (acc[mt][nt][2] + biasS[lm + 2]) * sc;
            float v3 = (acc[mt][nt][3] + biasS[lm + 3]) * sc;
            if (region < 2) {
                int mq = gm & 1023;
                int hh = mq >> 6, db = mq & 63;
                ushort_t* dst = (region == 0 ? Qo : Ko)
                              + (((size_t)b * HH + hh) * TT + t) * DD + db;
                uint2 pk;
                pk.x = packtrunc(v0, v1);
                pk.y = packtrunc(v2, v3);
                *(uint2*)dst = pk;
            } else {
                int c = gm & 1023;
                Vo[((size_t)b * CC + c + 0) * TT + t] = f2bf_t(v0);
                Vo[((size_t)b * CC + c + 1) * TT + t] = f2bf_t(v1);
                Vo[((size_t)b * CC + c + 2) * TT + t] = f2bf_t(v2);
                Vo[((size_t)b * CC + c + 3) * TT + t] = f2bf_t(v3);
            }
        }
    }
}

// ---------------------------------------------------------------------------
// Flash attention v11b (R5 exact — best measured: 42.2-42.8us).
//   - XCD-aware block swizzle: all 16 q-tile blocks sharing one
//     (head,batch,split) 256KB K/V slice land on ONE XCD -> K/V L2-resident.
//   - Rotation LDS swizzle: read-bank map 4*((ln31+cc)&7) == R1's proven
//     layout. glds dest linear, global source chunk rotated (both-sides).
// ---------------------------------------------------------------------------
__global__ __launch_bounds__(256, 4) void attn_kernel(
    const ushort_t* __restrict__ Qg, const ushort_t* __restrict__ Kg,
    const ushort_t* __restrict__ Vg, const int* __restrict__ nmcnt,
    ushort_t* __restrict__ Opart, float* __restrict__ lbuf) {
    // bytes [0,16384): K bufs (p*8192); [16384,32768): V bufs (16384+p*8192)
    __shared__ __align__(16) char ldsbuf[32768];

    // ---- XCD-aware decode: bid = xcd + 8*(x + 16*j), g = (j<<3)|xcd ----
    const unsigned int bid = blockIdx.x;          // 0..1023
    const unsigned int xcd = bid & 7u;
    const unsigned int rr  = bid >> 3;            // 0..127
    const unsigned int x   = rr & 15u;            // q-tile index
    const unsigned int j   = rr >> 4;             // 0..7
    const unsigned int g   = (j << 3) | xcd;      // 0..63 == hh + 16*z
    const int hh  = (int)(g & 15u);
    const int z   = (int)(g >> 4);                // 0..3 == sp + 2*b
    const int sp  = z & 1, b = z >> 1;
    const int t0  = (int)x * 128;

    const int j0base = sp * (TT / 2);
    const int tid  = threadIdx.x;
    const int lane = tid & 63;
    const int w    = tid >> 6;
    const int ln31 = lane & 31;
    const int h    = lane >> 5;
    const size_t qkbase = ((size_t)b * HH + hh) * TT * DD;
    const size_t vbase  = ((size_t)b * CC + hh * DD) * TT;

    const int tq = t0 + w * 32 + ln31;
    short8 qreg[4];
    {
        const ushort_t* qp = Qg + qkbase + (size_t)tq * DD + h * 8;
        #pragma unroll
        for (int kc = 0; kc < 4; kc++)
            qreg[kc] = *(const short8*)(qp + kc * 16);
    }

    // ---- staging geometry (rotation swizzle) ----
    const int i3   = lane >> 3;                          // 0..7 (row within 8)
    const int swzb = (((lane & 7) + 8 - i3) & 7) << 4;   // rotated byte-in-row
    const char* ks0 = (const char*)(Kg + qkbase + (size_t)(j0base + 16 * w + i3) * DD) + swzb;
    const char* vs0 = (const char*)(Vg + vbase + (size_t)(16 * w + i3) * TT + j0base) + swzb;
    char* kd = ldsbuf + 2 * w * 1024;                    // wave-uniform dests
    char* vd = ldsbuf + 16384 + 2 * w * 1024;

    // ---- rotated read addresses: G[row][chunk cc] lives at chunk (cc+row)&7
    int ka[4];
    #pragma unroll
    for (int kc = 0; kc < 4; kc++)
        ka[kc] = ln31 * 128 + (((kc * 2 + h + ln31) & 7) << 4);

    floatx16 zero16 = {0.f,0.f,0.f,0.f,0.f,0.f,0.f,0.f,
                       0.f,0.f,0.f,0.f,0.f,0.f,0.f,0.f};
    floatx16 oacc[2];
    oacc[0] = zero16; oacc[1] = zero16;
    floatx16 lacc = zero16;              // every reg = sum_k p[k][q]
    short8 ones8;
    #pragma unroll
    for (int i = 0; i < 8; i++) ones8[i] = (short)0x3F80;   // bf16 1.0

    // prologue: stage tile 0 into buf 0
    load_lds16(ks0,          kd);
    load_lds16(ks0 + 1024,   kd + 1024);     // q=1: +8 K rows = +1KB contiguous
    load_lds16(vs0,          vd);
    load_lds16(vs0 + 32768,  vd + 1024);     // q=1: +8 V rows = +8*TT*2 bytes
    ks0 += 8192; vs0 += 128;
    __syncthreads();   // drains vmcnt(0): tile 0 staged

    #pragma unroll 2
    for (int kt = 0; kt < 16; kt++) {
        const int pp = (kt & 1) * 8192;          // current buffer byte offset
        const int pn = 8192 - pp;                // next buffer byte offset
        // issue stage of tile kt+1 first: in flight during compute
        if (kt < 15) {
            load_lds16(ks0,         kd + pn);
            load_lds16(ks0 + 1024,  kd + pn + 1024);
            load_lds16(vs0,         vd + pn);
            load_lds16(vs0 + 32768, vd + pn + 1024);
            ks0 += 8192; vs0 += 128;
        }

        // ---- S^T = K · Q^T ----
        floatx16 sacc[2];
        sacc[0] = zero16; sacc[1] = zero16;
        __builtin_amdgcn_s_setprio(1);
        #pragma unroll
        for (int kc = 0; kc < 4; kc++) {
            short8 kf0 = *(const short8*)(ldsbuf + ka[kc] + pp);
            short8 kf1 = *(const short8*)(ldsbuf + ka[kc] + pp + 4096);
            sacc[0] = MFMA32(kf0, qreg[kc], sacc[0]);
            sacc[1] = MFMA32(kf1, qreg[kc], sacc[1]);
        }
        __builtin_amdgcn_s_setprio(0);

        // ---- bf16-domain Schraudolph: p_bf16 = low16(fma(s,128,PMAGIC)) ----
        unsigned int pd[16];
        #pragma unroll
        for (int mt = 0; mt < 2; mt++)
            #pragma unroll
            for (int g2 = 0; g2 < 4; g2++) {
                pd[mt * 8 + g2 * 2 + 0] =
                    pack2bf_exp(sacc[mt][g2 * 4 + 0], sacc[mt][g2 * 4 + 1]);
                pd[mt * 8 + g2 * 2 + 1] =
                    pack2bf_exp(sacc[mt][g2 * 4 + 2], sacc[mt][g2 * 4 + 3]);
            }

        // ---- PV: B-frag via permlane32_swap; l-sum via ones-MFMA ----
        __builtin_amdgcn_s_setprio(1);
        #pragma unroll
        for (int kc = 0; kc < 4; kc++) {
            const int base = (kc >> 1) * 8 + (kc & 1) * 4;
            uint2v r02 = __builtin_amdgcn_permlane32_swap(
                pd[base + 0], pd[base + 2], false, false);
            uint2v r13 = __builtin_amdgcn_permlane32_swap(
                pd[base + 1], pd[base + 3], false, false);
            int4 fi;
            fi.x = (int)r02[0];
            fi.y = (int)r13[0];
            fi.z = (int)r02[1];
            fi.w = (int)r13[1];
            short8 pf = *(short8*)&fi;
            lacc = MFMA32(ones8, pf, lacc);   // all rows = sum over k (both halves)
            short8 vf0 = *(const short8*)(ldsbuf + ka[kc] + pp + 16384);
            short8 vf1 = *(const short8*)(ldsbuf + ka[kc] + pp + 16384 + 4096);
            oacc[0] = MFMA32(vf0, pf, oacc[0]);
            oacc[1] = MFMA32(vf1, pf, oacc[1]);
        }
        __builtin_amdgcn_s_setprio(0);

        // barrier drains this wave's glds (vmcnt(0)) -> next buffer ready,
        // and guarantees all waves done reading buf pp before it's restaged.
        if (kt < 15) __syncthreads();
    }

    // lacc[0] holds the full split-sum over all 1024 keys. Remove masked
    // keys' exact bf16(approx 2^0) = 0.97265625 contributions.
    float lsum = lacc[0];
    {
        const int r4 = (b * 2 + sp) * 4;
        int nm = nmcnt[r4] + nmcnt[r4 + 1] + nmcnt[r4 + 2] + nmcnt[r4 + 3];
        lsum -= (float)nm * PZERO_BF;
    }

    // ---- epilogue: Opart = O_s/l_s (bf16 RNE — O-path stays unbiased) ----
    const float inv = lsum > 0.0f ? 1.0f / lsum : 0.0f;
    ushort_t* OP = Opart + (size_t)sp * ((size_t)BB * TT * CC)
                 + ((size_t)b * TT + tq) * CC + hh * 64;
    #pragma unroll
    for (int mt = 0; mt < 2; mt++)
        #pragma unroll
        for (int g2 = 0; g2 < 4; g2++) {
            int db = mt * 32 + g2 * 8 + h * 4;
            ushort4 pk;
            pk.x = f2bf(oacc[mt][g2 * 4 + 0] * inv);
            pk.y = f2bf(oacc[mt][g2 * 4 + 1] * inv);
            pk.z = f2bf(oacc[mt][g2 * 4 + 2] * inv);
            pk.w = f2bf(oacc[mt][g2 * 4 + 3] * inv);
            *(ushort4*)&OP[db] = pk;
        }
    if (h == 0)
        lbuf[(((size_t)sp * BB + b) * HH + hh) * TT + tq] = lsum;
}

// ---------------------------------------------------------------------------
// Combine splits: OT = w0*P0 + w1*P1, w_s = l_s/(l0+l1).
// ---------------------------------------------------------------------------
__global__ __launch_bounds__(256) void combine_kernel(
    const ushort_t* __restrict__ Opart, const float* __restrict__ lbuf,
    ushort_t* __restrict__ OT) {
    const size_t idx = ((size_t)blockIdx.x * 256 + threadIdx.x) * 8;
    const int c0 = (int)(idx & (CC - 1));
    const int t  = (int)((idx >> 10) & (TT - 1));
    const int b  = (int)(idx >> 21);
    const int hh = c0 >> 6;
    const float l0 = lbuf[(((size_t)0 * BB + b) * HH + hh) * TT + t];
    const float l1 = lbuf[(((size_t)1 * BB + b) * HH + hh) * TT + t];
    const float sum = l0 + l1;
    const float ws = sum > 0.0f ? 1.0f / sum : 0.0f;
    const float w0 = l0 * ws, w1 = l1 * ws;
    const ushort_t* P0 = Opart + idx;
    const ushort_t* P1 = Opart + (size_t)BB * TT * CC + idx;
    ushort4 a0 = *(const ushort4*)(P0);
    ushort4 a1 = *(const ushort4*)(P0 + 4);
    ushort4 b0 = *(const ushort4*)(P1);
    ushort4 b1 = *(const ushort4*)(P1 + 4);
    ushort4 o0, o1;
    o0.x = f2bf(w0 * bf2f(a0.x) + w1 * bf2f(b0.x));
    o0.y = f2bf(w0 * bf2f(a0.y) + w1 * bf2f(b0.y));
    o0.z = f2bf(w0 * bf2f(a0.z) + w1 * bf2f(b0.z));
    o0.w = f2bf(w0 * bf2f(a0.w) + w1 * bf2f(b0.w));
    o1.x = f2bf(w0 * bf2f(a1.x) + w1 * bf2f(b1.x));
    o1.y = f2bf(w0 * bf2f(a1.y) + w1 * bf2f(b1.y));
    o1.z = f2bf(w0 * bf2f(a1.z) + w1 * bf2f(b1.z));
    o1.w = f2bf(w0 * bf2f(a1.w) + w1 * bf2f(b1.w));
    *(ushort4*)&OT[idx]     = o0;
    *(ushort4*)&OT[idx + 4] = o1;
}

// ---------------------------------------------------------------------------
// Output GEMM, single-pass bf16 (proven R7/R8).
// ---------------------------------------------------------------------------
__global__ __launch_bounds__(256) void gemm_out_kernel(
    const ushort_t* __restrict__ WP, const ushort_t* __restrict__ OT,
    const float* __restrict__ bp, const float* __restrict__ maskf,
    float* __restrict__ out) {
    __shared__ ushort_t As[64][32];
    __shared__ ushort_t Bs[128][32];
    __shared__ float biasS[64];

    const int b = blockIdx.z;
    const int m0 = blockIdx.y * 64;
    const int n0 = blockIdx.x * 128;
    const int tid = threadIdx.x;
    const int lane = tid & 63;
    const int w = tid >> 6;
    const int wm = (w & 1) * 32, wn = (w >> 1) * 64;
    const int la = lane & 15, lg = lane >> 4;

    if (tid < 64) biasS[tid] = bp[m0 + tid];

    floatx4 zero4 = {0.f, 0.f, 0.f, 0.f};
    floatx4 acc[2][4];
    #pragma unroll
    for (int mt = 0; mt < 2; mt++)
        #pragma unroll
        for (int nt = 0; nt < 4; nt++) acc[mt][nt] = zero4;

    const int rl = lane >> 2;
    const int cl = (lane & 3) * 8;
    const ushort_t* Bbase = OT + ((size_t)b * TT + n0) * CC;

    for (int k0 = 0; k0 < CC; k0 += 32) {
        {
            int row = w * 16;
            load_lds16(WP + (size_t)(m0 + row + rl) * CC + k0 + cl, &As[row][0]);
        }
        #pragma unroll
        for (int c = 0; c < 2; c++) {
            int row = w * 32 + c * 16;
            load_lds16(Bbase + (size_t)(row + rl) * CC + k0 + cl, &Bs[row][0]);
        }
        __syncthreads();
        short8 af[2], bf[4];
        #pragma unroll
        for (int mt = 0; mt < 2; mt++)
            af[mt] = *(const short8*)&As[wm + mt * 16 + la][lg * 8];
        #pragma unroll
        for (int nt = 0; nt < 4; nt++)
            bf[nt] = *(const short8*)&Bs[wn + nt * 16 + la][lg * 8];
        #pragma unroll
        for (int mt = 0; mt < 2; mt++)
            #pragma unroll
            for (int nt = 0; nt < 4; nt++)
                acc[mt][nt] = MFMA(af[mt], bf[nt], acc[mt][nt]);
        __syncthreads();
    }

    #pragma unroll
    for (int mt = 0; mt < 2; mt++) {
        const int lm = wm + mt * 16 + lg * 4;
        #pragma unroll
        for (int nt = 0; nt < 4; nt++) {
            const int t = n0 + wn + nt * 16 + la;
            const float mk = maskf[b * TT + t];
            #pragma unroll
            for (int r = 0; r < 4; r++)
                out[((size_t)b * CC + m0 + lm + r) * TT + t] =
                    (acc[mt][nt][r] + biasS[lm + r]) * mk;
        }
    }
}

// ---------------------------------------------------------------------------
extern "C" void kernel_launch(void* const* d_in, const int* in_sizes, int n_in,
                              void* d_out, int out_size, void* d_ws,
                              size_t ws_size, hipStream_t stream) {
    const float* x    = (const float*)d_in[0];
    const void*  mask = d_in[1];
    const float* Wq   = (const float*)d_in[2];
    const float* bq   = (const float*)d_in[3];
    const float* Wk   = (const float*)d_in[4];
    const float* bk   = (const float*)d_in[5];
    const float* Wv   = (const float*)d_in[6];
    const float* bv   = (const float*)d_in[7];
    const float* Wp   = (const float*)d_in[8];
    const float* bp   = (const float*)d_in[9];

    float* out  = (float*)d_out;
    float* wsf  = (float*)d_ws;
    int* nmcnt  = (int*)d_ws + 16;     // 16 per-block masked counts
    float* maskf = wsf + 1024;
    char* wsb = (char*)d_ws;
    ushort_t* XT    = (ushort_t*)(wsb + XT_OFF);   // also final OT
    ushort_t* WQKV  = (ushort_t*)(wsb + WQKV_OFF);
    ushort_t* WPb   = (ushort_t*)(wsb + WP_OFF);
    ushort_t* Qb    = (ushort_t*)(wsb + Q_OFF);
    ushort_t* Kb    = (ushort_t*)(wsb + K_OFF);
    ushort_t* Vb    = (ushort_t*)(wsb + V_OFF);
    ushort_t* Opart = (ushort_t*)(wsb + OP_OFF);
    float*    lbuf  = (float*)(wsb + ML_OFF);

    prep_kernel<<<5136, 256, 0, stream>>>(x, Wq, Wk, Wv, Wp,
                                          (const unsigned int*)mask, XT, WQKV,
                                          WPb, maskf, nmcnt,
                                          out + (size_t)BB * CC * TT);

    gemm_qkv_kernel<<<dim3(TT / 128, 3 * CC / 128, BB), 256, 0, stream>>>(
        WQKV, bq, bk, bv, XT, maskf, Qb, Kb, Vb);

    attn_kernel<<<dim3(1024), 256, 0, stream>>>(
        Qb, Kb, Vb, nmcnt, Opart, lbuf);

    combine_kernel<<<2048, 256, 0, stream>>>(Opart, lbuf, XT);

    gemm_out_kernel<<<dim3(TT / 128, CC / 64, BB), 256, 0, stream>>>(
        WPb, XT, bp, maskf, out);
}